// Round 6
// baseline (827.092 us; speedup 1.0000x reference)
//
#include <hip/hip_runtime.h>
#include <cstdint>

// Problem constants (B,T,N,E)=(32,512,4,16), NI=16, EI=8, HN=HE=128, MH=256, C=8
constexpr int T_  = 512;
constexpr int HN_ = 128;

#define DEVI __device__ __forceinline__

typedef __bf16 bf16x8 __attribute__((ext_vector_type(8)));
typedef __bf16 bf16x4 __attribute__((ext_vector_type(4)));
typedef __bf16 bf16x2 __attribute__((ext_vector_type(2)));
typedef float  f32x4  __attribute__((ext_vector_type(4)));

DEVI float sigf(float x) { return __builtin_amdgcn_rcpf(1.f + __expf(-x)); }
DEVI float tanh_fast(float x) {
  x = fminf(fmaxf(x, -15.f), 15.f);
  return 1.f - 2.f * __builtin_amdgcn_rcpf(1.f + __expf(2.f * x));
}
DEVI float swz_xor8(float x) {   // value from lane^8 (BitMode xor=8)
  return __int_as_float(__builtin_amdgcn_ds_swizzle(__float_as_int(x), 0x201F));
}

// ---- shared MFMA layer helpers (64-row tile, 128->128, wave w owns cols n)
DEVI void layer128_bf(const __bf16* __restrict__ src, __bf16* __restrict__ dst,
                      bf16x8 w0, bf16x8 w1, bf16x8 w2, bf16x8 w3,
                      float bv, int lm, int lh, int n)
{
  #pragma unroll
  for (int m = 0; m < 4; ++m) {
    const __bf16* sp = &src[(m*16 + lm)*136 + lh*8];
    const bf16x8 a0 = *reinterpret_cast<const bf16x8*>(sp);
    const bf16x8 a1 = *reinterpret_cast<const bf16x8*>(sp + 32);
    const bf16x8 a2 = *reinterpret_cast<const bf16x8*>(sp + 64);
    const bf16x8 a3 = *reinterpret_cast<const bf16x8*>(sp + 96);
    f32x4 acc = { bv, bv, bv, bv };
    acc = __builtin_amdgcn_mfma_f32_16x16x32_bf16(a0, w0, acc, 0, 0, 0);
    acc = __builtin_amdgcn_mfma_f32_16x16x32_bf16(a1, w1, acc, 0, 0, 0);
    acc = __builtin_amdgcn_mfma_f32_16x16x32_bf16(a2, w2, acc, 0, 0, 0);
    acc = __builtin_amdgcn_mfma_f32_16x16x32_bf16(a3, w3, acc, 0, 0, 0);
    #pragma unroll
    for (int r = 0; r < 4; ++r)
      dst[(m*16 + lh*4 + r)*136 + n] = (__bf16)fmaxf(acc[r], 0.f);
  }
}

DEVI void layer128_f32(const __bf16* __restrict__ src, float* __restrict__ dst,
                       bf16x8 w0, bf16x8 w1, bf16x8 w2, bf16x8 w3,
                       float bv, bool relu, int lm, int lh, int n)
{
  #pragma unroll
  for (int m = 0; m < 4; ++m) {
    const __bf16* sp = &src[(m*16 + lm)*136 + lh*8];
    const bf16x8 a0 = *reinterpret_cast<const bf16x8*>(sp);
    const bf16x8 a1 = *reinterpret_cast<const bf16x8*>(sp + 32);
    const bf16x8 a2 = *reinterpret_cast<const bf16x8*>(sp + 64);
    const bf16x8 a3 = *reinterpret_cast<const bf16x8*>(sp + 96);
    f32x4 acc = { bv, bv, bv, bv };
    acc = __builtin_amdgcn_mfma_f32_16x16x32_bf16(a0, w0, acc, 0, 0, 0);
    acc = __builtin_amdgcn_mfma_f32_16x16x32_bf16(a1, w1, acc, 0, 0, 0);
    acc = __builtin_amdgcn_mfma_f32_16x16x32_bf16(a2, w2, acc, 0, 0, 0);
    acc = __builtin_amdgcn_mfma_f32_16x16x32_bf16(a3, w3, acc, 0, 0, 0);
    #pragma unroll
    for (int r = 0; r < 4; ++r)
      dst[(m*16 + lh*4 + r)*132 + n] = relu ? fmaxf(acc[r], 0.f) : acc[r];
  }
}

// ---------------- K1: node MLP + 2 graph-conv layers (MFMA) -> xn
__global__ __launch_bounds__(512, 4) void node_mlp_mfma_kernel(
    const float* __restrict__ x_seq,
    const float* __restrict__ Wn1, const float* __restrict__ bn1,
    const float* __restrict__ Wn2, const float* __restrict__ bn2,
    const float* __restrict__ Wg1, const float* __restrict__ bg1,
    const float* __restrict__ Wg2, const float* __restrict__ bg2,
    float* __restrict__ xn)
{
  constexpr int P1 = 40;
  __shared__ __align__(16) __bf16 A1[64 * P1];
  __shared__ __align__(16) __bf16 Ab[64 * 136];
  __shared__ __align__(16) __bf16 Bb[64 * 136];
  __shared__ __align__(16) float  Yf[64 * 132];

  const int tid = threadIdx.x;
  const int w = tid >> 6, l = tid & 63, lm = l & 15, lh = l >> 4;
  const int n = w*16 + lm;

  bf16x8 w1, w2[4], w3[4], w4[4];
  const float b1 = bn1[n], b2 = bn2[n];
  #pragma unroll
  for (int j = 0; j < 8; ++j) {
    const int k = lh*8 + j;
    w1[j] = (k < 16) ? (__bf16)Wn1[k*128 + n] : (__bf16)0.f;
  }
  #pragma unroll
  for (int kt = 0; kt < 4; ++kt)
    #pragma unroll
    for (int j = 0; j < 8; ++j) {
      const int k = kt*32 + lh*8 + j;
      w2[kt][j] = (__bf16)Wn2[k*128 + n];
      w3[kt][j] = (__bf16)Wg1[k*128 + n];
      w4[kt][j] = (__bf16)Wg2[k*128 + n];
    }

  for (int i = tid; i < 64 * P1; i += 512) A1[i] = (__bf16)0.f;

  for (int g = blockIdx.x; g < 1024; g += 512) {
    #pragma unroll
    for (int it = 0; it < 2; ++it) {
      const int i = tid + it*512;
      A1[(i >> 4)*P1 + (i & 15)] = (__bf16)x_seq[(size_t)g*1024 + i];
    }
    __syncthreads();
    #pragma unroll
    for (int m = 0; m < 4; ++m) {
      const bf16x8 a = *reinterpret_cast<const bf16x8*>(&A1[(m*16+lm)*P1 + lh*8]);
      f32x4 acc = { b1, b1, b1, b1 };
      acc = __builtin_amdgcn_mfma_f32_16x16x32_bf16(a, w1, acc, 0, 0, 0);
      #pragma unroll
      for (int r = 0; r < 4; ++r)
        Ab[(m*16 + lh*4 + r)*136 + n] = (__bf16)fmaxf(acc[r], 0.f);
    }
    __syncthreads();
    layer128_bf(Ab, Bb, w2[0], w2[1], w2[2], w2[3], b2, lm, lh, n);   // L2
    __syncthreads();
    layer128_f32(Bb, Yf, w3[0], w3[1], w3[2], w3[3], 0.f, false, lm, lh, n); // G1
    __syncthreads();
    #pragma unroll
    for (int it = 0; it < 4; ++it) {
      const int idx = tid + it*512;
      const int q = idx >> 7, d = idx & 127;
      const float y0 = Yf[(q*4+0)*132 + d], y1 = Yf[(q*4+1)*132 + d];
      const float y2 = Yf[(q*4+2)*132 + d], y3 = Yf[(q*4+3)*132 + d];
      const float s = y0 + y1 + y2 + y3;
      const float bv = bg1[d];
      Ab[(q*4+0)*136 + d] = (__bf16)fmaxf((s + y0)*0.2f + bv, 0.f);
      Ab[(q*4+1)*136 + d] = (__bf16)fmaxf((s + y1)*0.2f + bv, 0.f);
      Ab[(q*4+2)*136 + d] = (__bf16)fmaxf((s + y2)*0.2f + bv, 0.f);
      Ab[(q*4+3)*136 + d] = (__bf16)fmaxf((s + y3)*0.2f + bv, 0.f);
    }
    __syncthreads();
    layer128_f32(Ab, Yf, w4[0], w4[1], w4[2], w4[3], 0.f, false, lm, lh, n); // G2
    __syncthreads();
    #pragma unroll
    for (int it = 0; it < 4; ++it) {
      const int idx = tid + it*512;
      const int q = idx >> 7, d = idx & 127;
      const int bt = g*16 + q, bb = bt >> 9, tt = bt & 511;
      const float y0 = Yf[(q*4+0)*132 + d], y1 = Yf[(q*4+1)*132 + d];
      const float y2 = Yf[(q*4+2)*132 + d], y3 = Yf[(q*4+3)*132 + d];
      const float s = y0 + y1 + y2 + y3;
      const float bv = bg2[d];
      xn[((size_t)(bb*4+0)*T_ + tt)*HN_ + d] = fmaxf((s + y0)*0.2f + bv, 0.f);
      xn[((size_t)(bb*4+1)*T_ + tt)*HN_ + d] = fmaxf((s + y1)*0.2f + bv, 0.f);
      xn[((size_t)(bb*4+2)*T_ + tt)*HN_ + d] = fmaxf((s + y2)*0.2f + bv, 0.f);
      xn[((size_t)(bb*4+3)*T_ + tt)*HN_ + d] = fmaxf((s + y3)*0.2f + bv, 0.f);
    }
    __syncthreads();
  }
}

// ---------------- K2: edge MLP (4 layers, MFMA) -> en
__global__ __launch_bounds__(512, 4) void edge_mlp_mfma_kernel(
    const float* __restrict__ ea,
    const float* __restrict__ We1, const float* __restrict__ be1,
    const float* __restrict__ We2, const float* __restrict__ be2,
    const float* __restrict__ Wef1, const float* __restrict__ bef1,
    const float* __restrict__ Wef2, const float* __restrict__ bef2,
    float* __restrict__ en)
{
  constexpr int P1 = 40;
  __shared__ __align__(16) __bf16 A1[64 * P1];
  __shared__ __align__(16) __bf16 Ab[64 * 136];
  __shared__ __align__(16) __bf16 Bb[64 * 136];
  __shared__ __align__(16) float  Of[64 * 132];

  const int tid = threadIdx.x;
  const int w = tid >> 6, l = tid & 63, lm = l & 15, lh = l >> 4;
  const int n = w*16 + lm;

  bf16x8 w1, w2[4], w3[4], w4[4];
  const float b1 = be1[n], b2 = be2[n], b3 = bef1[n], b4 = bef2[n];
  #pragma unroll
  for (int j = 0; j < 8; ++j) {
    const int k = lh*8 + j;
    w1[j] = (k < 8) ? (__bf16)We1[k*128 + n] : (__bf16)0.f;
  }
  #pragma unroll
  for (int kt = 0; kt < 4; ++kt)
    #pragma unroll
    for (int j = 0; j < 8; ++j) {
      const int k = kt*32 + lh*8 + j;
      w2[kt][j] = (__bf16)We2[k*128 + n];
      w3[kt][j] = (__bf16)Wef1[k*128 + n];
      w4[kt][j] = (__bf16)Wef2[k*128 + n];
    }

  for (int i = tid; i < 64 * P1; i += 512) A1[i] = (__bf16)0.f;

  for (int g = blockIdx.x; g < 4096; g += 512) {
    A1[(tid >> 3)*P1 + (tid & 7)] = (__bf16)ea[(size_t)g*512 + tid];
    __syncthreads();
    #pragma unroll
    for (int m = 0; m < 4; ++m) {
      const bf16x8 a = *reinterpret_cast<const bf16x8*>(&A1[(m*16+lm)*P1 + lh*8]);
      f32x4 acc = { b1, b1, b1, b1 };
      acc = __builtin_amdgcn_mfma_f32_16x16x32_bf16(a, w1, acc, 0, 0, 0);
      #pragma unroll
      for (int r = 0; r < 4; ++r)
        Ab[(m*16 + lh*4 + r)*136 + n] = (__bf16)fmaxf(acc[r], 0.f);
    }
    __syncthreads();
    layer128_bf(Ab, Bb, w2[0], w2[1], w2[2], w2[3], b2, lm, lh, n);          // L2
    __syncthreads();
    layer128_bf(Bb, Ab, w3[0], w3[1], w3[2], w3[3], b3, lm, lh, n);          // L3
    __syncthreads();
    layer128_f32(Ab, Of, w4[0], w4[1], w4[2], w4[3], b4, true, lm, lh, n);   // L4
    __syncthreads();
    #pragma unroll
    for (int i = 0; i < 4; ++i) {
      const int fi = tid + i*512;
      const int row = fi >> 5, c4 = fi & 31;
      const int q = row >> 4, e = row & 15;
      const int bt = g*4 + q, bb = bt >> 9, tt = bt & 511;
      const float4 v = *reinterpret_cast<const float4*>(&Of[row*132 + c4*4]);
      *reinterpret_cast<float4*>(
          &en[((size_t)(bb*16+e)*T_ + tt)*HN_ + c4*4]) = v;
    }
    __syncthreads();
  }
}

// ---------------- K3: fused MFMA LSTM, swapped operands, XOR-swizzled LDS
// All LDS tiles swizzled as byte_col ^= ((row&7)<<4) at 16B granularity:
// fragment reads are bank-uniform (was 8-way conflicted at pitch=8-bank).
// accA (Wih chain) and accB (Whh chain) split -> 4-deep dependent MFMA.
// bx fragments for step t+1 prefetched before the barrier (x_c chunk-stable).
__global__ __launch_bounds__(512, 1) void lstm_mfma_kernel(
    const float* __restrict__ Wih_n, const float* __restrict__ Whh_n,
    const float* __restrict__ b_n,
    const float* __restrict__ Wih_e, const float* __restrict__ Whh_e,
    const float* __restrict__ b_e,
    float* __restrict__ xn, float* __restrict__ en)
{
  __shared__ __align__(16) __bf16 x_c[8 * 2048];    // 8 seq x 16t x 128, 4096B rows
  __shared__ __align__(16) __bf16 x_zero[2048];
  __shared__ __align__(16) __bf16 h_bf[8 * 128];    // 256B rows
  __shared__ __align__(16) __bf16 h_zero[128];
  __shared__ __align__(16) float  h_hist[8 * 2048]; // 8192B rows

  const bool is_node = (int)blockIdx.x < 16;
  const int  bidx    = is_node ? blockIdx.x : ((int)blockIdx.x - 16);
  const float* __restrict__ Wih  = is_node ? Wih_n : Wih_e;
  const float* __restrict__ Whh  = is_node ? Whh_n : Whh_e;
  const float* __restrict__ bias = is_node ? b_n   : b_e;
  float* __restrict__ xh = (is_node ? xn : en) + (size_t)bidx * 8 * (T_ * HN_);

  const int tid = threadIdx.x;
  const int w   = tid >> 6;       // wave 0..7 -> dims [16w,16w+16)
  const int l   = tid & 63;
  const int lm  = l & 15;         // A row (gate) / B col (seq)
  const int lh  = l >> 4;

  // A-operand fragments: A[m][k] = W[k][gate], m=lm, k=kt*32+lh*8+j
  bf16x8 wih_f[4][4], whh_f[4][4];
  f32x4  bias_v[4];
  #pragma unroll
  for (int nt = 0; nt < 4; ++nt) {
    const int g0 = nt*128 + w*16;
    bias_v[nt] = *reinterpret_cast<const f32x4*>(&bias[g0 + lh*4]);
    #pragma unroll
    for (int kt = 0; kt < 4; ++kt) {
      #pragma unroll
      for (int j = 0; j < 8; ++j) {
        const int k = kt*32 + lh*8 + j;
        wih_f[nt][kt][j] = (__bf16)Wih[k*512 + g0 + lm];
        whh_f[nt][kt][j] = (__bf16)Whh[k*512 + g0 + lm];
      }
    }
  }

  for (int i = tid; i < 2048; i += 512) x_zero[i] = (__bf16)0.f;
  for (int i = tid; i < 8 * 128; i += 512) h_bf[i] = (__bf16)0.f;
  if (tid < 128) h_zero[tid] = (__bf16)0.f;

  // B-row pointers; lm>=8 -> zero rows (unswizzled, same-address broadcast)
  const int swz = (lm < 8) ? ((lm & 7) << 4) : 0;
  const __bf16* __restrict__ xrow = (lm < 8) ? &x_c[lm * 2048] : x_zero;
  const __bf16* __restrict__ hrow = (lm < 8) ? &h_bf[lm * 128] : h_zero;
  int foff[4];   // swizzled bf16 offset of fragment kt within a 256B row-step
  #pragma unroll
  for (int kt = 0; kt < 4; ++kt)
    foff[kt] = ((kt*64 + lh*16) ^ swz) >> 1;

  const bool hi_half = lm >= 8;
  const int  s  = lm & 7;
  // swizzled store index for h_bf (bf16x2 per thread)
  const int hb_unit = (2*w + (lh >> 1)) ^ s;
  const int hb_idx  = s*128 + (((hb_unit << 4) + 8*(lh & 1) + (hi_half ? 4 : 0)) >> 1);
  // swizzled column unit for h_hist (float2 per thread)
  const int hh_col  = (w*4 + lh) ^ s;
  const int hh_base = s*2048 + hh_col*4 + (hi_half ? 2 : 0);
  float c0 = 0.f, c1 = 0.f;

  bf16x8 bx[4];
  for (int t = 0; t < T_; ++t) {
    const int tl = t & 15;
    if (tl == 0) {
      if (t) {  // bulk flush h for steps t-16..t-1
        #pragma unroll
        for (int i = 0; i < 8; ++i) {
          const int tl2 = tid >> 5, u = tid & 31;
          const float4 v = *reinterpret_cast<const float4*>(
              &h_hist[i*2048 + (tid ^ (i & 7))*4]);
          *reinterpret_cast<float4*>(
              &xh[(size_t)i*(T_*HN_) + (size_t)(t-16+tl2)*HN_ + u*4]) = v;
        }
      }
      // stage x chunk t..t+15 (seq i: 512 thr x 4 f32 = one row)
      #pragma unroll
      for (int i = 0; i < 8; ++i) {
        const float4 v = *reinterpret_cast<const float4*>(
            &xh[(size_t)i*(T_*HN_) + (size_t)t*HN_ + tid*4]);
        bf16x4 pk;
        pk[0] = (__bf16)v.x; pk[1] = (__bf16)v.y;
        pk[2] = (__bf16)v.z; pk[3] = (__bf16)v.w;
        *reinterpret_cast<bf16x4*>(
            &x_c[i*2048 + (((tid >> 1) ^ (i & 7)) << 3) + (tid & 1)*4]) = pk;
      }
      __syncthreads();
      #pragma unroll
      for (int kt = 0; kt < 4; ++kt)
        bx[kt] = *reinterpret_cast<const bf16x8*>(&xrow[foff[kt]]);
    }

    // ---- bh fragments (depend on last step's h)
    bf16x8 bh[4];
    #pragma unroll
    for (int kt = 0; kt < 4; ++kt)
      bh[kt] = *reinterpret_cast<const bf16x8*>(&hrow[foff[kt]]);

    // ---- z^T = bias + Wih^T@x (chain A) + Whh^T@h (chain B)
    f32x4 accs[4];
    #pragma unroll
    for (int nt = 0; nt < 4; ++nt) {
      f32x4 aA = bias_v[nt];
      f32x4 aB = { 0.f, 0.f, 0.f, 0.f };
      #pragma unroll
      for (int kt = 0; kt < 4; ++kt) {
        aA = __builtin_amdgcn_mfma_f32_16x16x32_bf16(wih_f[nt][kt], bx[kt], aA, 0, 0, 0);
        aB = __builtin_amdgcn_mfma_f32_16x16x32_bf16(whh_f[nt][kt], bh[kt], aB, 0, 0, 0);
      }
      accs[nt] = aA + aB;
    }

    // ---- prefetch next step's bx (x_c stable within chunk; overlaps gates)
    if (tl != 15) {
      #pragma unroll
      for (int kt = 0; kt < 4; ++kt)
        bx[kt] = *reinterpret_cast<const bf16x8*>(&xrow[(tl+1)*128 + foff[kt]]);
    }

    // ---- in-register gates; lanes lm>=8 take rows r=2,3 via ds_swizzle xor-8
    float z0[4], z1[4];
    #pragma unroll
    for (int nt = 0; nt < 4; ++nt) {
      const float a2 = swz_xor8(accs[nt][2]);
      const float a3 = swz_xor8(accs[nt][3]);
      z0[nt] = hi_half ? a2 : accs[nt][0];
      z1[nt] = hi_half ? a3 : accs[nt][1];
    }
    c0 = sigf(z0[1]) * c0 + sigf(z0[0]) * tanh_fast(z0[2]);
    const float h0 = sigf(z0[3]) * tanh_fast(c0);
    c1 = sigf(z1[1]) * c1 + sigf(z1[0]) * tanh_fast(z1[2]);
    const float h1 = sigf(z1[3]) * tanh_fast(c1);

    bf16x2 hb; hb[0] = (__bf16)h0; hb[1] = (__bf16)h1;
    *reinterpret_cast<bf16x2*>(&h_bf[hb_idx]) = hb;
    float2 ho; ho.x = h0; ho.y = h1;
    *reinterpret_cast<float2*>(&h_hist[hh_base + tl*128]) = ho;
    __syncthreads();
  }
  // final flush (steps 496..511)
  #pragma unroll
  for (int i = 0; i < 8; ++i) {
    const int tl2 = tid >> 5, u = tid & 31;
    const float4 v = *reinterpret_cast<const float4*>(
        &h_hist[i*2048 + (tid ^ (i & 7))*4]);
    *reinterpret_cast<float4*>(
        &xh[(size_t)i*(T_*HN_) + (size_t)(T_-16+tl2)*HN_ + u*4]) = v;
  }
}

// ---------------- K4: MFMA gather + classifier (384 -> 256 -> 8)
__global__ __launch_bounds__(512, 1) void classifier_mfma_kernel(
    const float* __restrict__ hn, const float* __restrict__ he,
    const float* __restrict__ Wc1, const float* __restrict__ bc1,
    const float* __restrict__ Wc2, const float* __restrict__ bc2,
    float* __restrict__ out)
{
  constexpr int HP = 136;
  constexpr int DP = 264;
  __shared__ __align__(16) __bf16 hn_l[32 * HP];
  __shared__ __align__(16) __bf16 he_l[128 * HP];
  __shared__ __align__(16) __bf16 hid_l[128 * DP];

  const int tid = threadIdx.x;
  const int w   = tid >> 6;
  const int l   = tid & 63;
  const int lm  = l & 15;
  const int lh  = l >> 4;

  bf16x8 wb[2][12];
  float  bcol[2];
  #pragma unroll
  for (int jt = 0; jt < 2; ++jt) {
    const int j = w*32 + jt*16 + lm;
    bcol[jt] = bc1[j];
    #pragma unroll
    for (int kt = 0; kt < 12; ++kt)
      #pragma unroll
      for (int i = 0; i < 8; ++i)
        wb[jt][kt][i] = (__bf16)Wc1[(kt*32 + lh*8 + i)*256 + j];
  }
  bf16x8 wc2f[8];
  const float bc2v = (lm < 8) ? bc2[lm] : 0.f;
  #pragma unroll
  for (int kt = 0; kt < 8; ++kt)
    #pragma unroll
    for (int i = 0; i < 8; ++i)
      wc2f[kt][i] = (lm < 8) ? (__bf16)Wc2[(kt*32 + lh*8 + i)*8 + lm] : (__bf16)0.f;

  for (int g = blockIdx.x; g < 2048; g += 256) {
    const int b  = g >> 6;
    const int t0 = (g & 63) * 8;

    for (int i = tid; i < 4096; i += 512) {
      const int f4 = i * 4;
      const int e  = f4 >> 10;
      const int rem = f4 & 1023;
      const int tt = rem >> 7;
      const int k  = rem & 127;
      const float4 v = *reinterpret_cast<const float4*>(
          &he[((size_t)(b*16+e)*T_ + t0 + tt)*HN_ + k]);
      __bf16* p = &he_l[(tt*16 + e)*HP + k];
      p[0]=(__bf16)v.x; p[1]=(__bf16)v.y; p[2]=(__bf16)v.z; p[3]=(__bf16)v.w;
    }
    for (int i = tid; i < 1024; i += 512) {
      const int f4 = i * 4;
      const int n  = f4 >> 10;
      const int rem = f4 & 1023;
      const int tt = rem >> 7;
      const int k  = rem & 127;
      const float4 v = *reinterpret_cast<const float4*>(
          &hn[((size_t)(b*4+n)*T_ + t0 + tt)*HN_ + k]);
      __bf16* p = &hn_l[(tt*4 + n)*HP + k];
      p[0]=(__bf16)v.x; p[1]=(__bf16)v.y; p[2]=(__bf16)v.z; p[3]=(__bf16)v.w;
    }
    __syncthreads();

    for (int tt = 0; tt < 8; ++tt) {
      bf16x8 af[12];
      #pragma unroll
      for (int kt = 0; kt < 4; ++kt)
        af[kt] = *reinterpret_cast<const bf16x8*>(
            &hn_l[(tt*4 + (lm>>2))*HP + kt*32 + lh*8]);
      #pragma unroll
      for (int kt = 0; kt < 4; ++kt)
        af[4+kt] = *reinterpret_cast<const bf16x8*>(
            &hn_l[(tt*4 + (lm&3))*HP + kt*32 + lh*8]);
      #pragma unroll
      for (int kt = 0; kt < 4; ++kt)
        af[8+kt] = *reinterpret_cast<const bf16x8*>(
            &he_l[(tt*16 + lm)*HP + kt*32 + lh*8]);
      #pragma unroll
      for (int jt = 0; jt < 2; ++jt) {
        f32x4 acc = { bcol[jt], bcol[jt], bcol[jt], bcol[jt] };
        #pragma unroll
        for (int kt = 0; kt < 12; ++kt)
          acc = __builtin_amdgcn_mfma_f32_16x16x32_bf16(af[kt], wb[jt][kt], acc, 0, 0, 0);
        #pragma unroll
        for (int r = 0; r < 4; ++r)
          hid_l[(tt*16 + lh*4 + r)*DP + (w*2 + jt)*16 + lm] = (__bf16)fmaxf(acc[r], 0.f);
      }
    }
    __syncthreads();

    {
      const int tt = w;
      f32x4 acc = { bc2v, bc2v, bc2v, bc2v };
      #pragma unroll
      for (int kt = 0; kt < 8; ++kt) {
        const bf16x8 a = *reinterpret_cast<const bf16x8*>(
            &hid_l[(tt*16 + lm)*DP + kt*32 + lh*8]);
        acc = __builtin_amdgcn_mfma_f32_16x16x32_bf16(a, wc2f[kt], acc, 0, 0, 0);
      }
      if (lm < 8) {
        const size_t bt = (size_t)b*T_ + t0 + tt;
        #pragma unroll
        for (int r = 0; r < 4; ++r)
          out[(bt*16 + lh*4 + r)*8 + lm] = acc[r];
      }
    }
    __syncthreads();
  }
}

extern "C" void kernel_launch(void* const* d_in, const int* in_sizes, int n_in,
                              void* d_out, int out_size, void* d_ws, size_t ws_size,
                              hipStream_t stream) {
  (void)in_sizes; (void)n_in; (void)out_size; (void)ws_size;
  const float* x_seq = (const float*)d_in[0];
  const float* ea    = (const float*)d_in[1];
  const float* Wn1 = (const float*)d_in[2];
  const float* bn1 = (const float*)d_in[3];
  const float* Wn2 = (const float*)d_in[4];
  const float* bn2 = (const float*)d_in[5];
  const float* We1 = (const float*)d_in[6];
  const float* be1 = (const float*)d_in[7];
  const float* We2 = (const float*)d_in[8];
  const float* be2 = (const float*)d_in[9];
  const float* Wg1 = (const float*)d_in[10];
  const float* bg1 = (const float*)d_in[11];
  const float* Wg2 = (const float*)d_in[12];
  const float* bg2 = (const float*)d_in[13];
  const float* Wef1 = (const float*)d_in[14];
  const float* bef1 = (const float*)d_in[15];
  const float* Wef2 = (const float*)d_in[16];
  const float* bef2 = (const float*)d_in[17];
  const float* Wih_n = (const float*)d_in[18];
  const float* Whh_n = (const float*)d_in[19];
  const float* b_n   = (const float*)d_in[20];
  const float* Wih_e = (const float*)d_in[21];
  const float* Whh_e = (const float*)d_in[22];
  const float* b_e   = (const float*)d_in[23];
  const float* Wc1 = (const float*)d_in[24];
  const float* bc1 = (const float*)d_in[25];
  const float* Wc2 = (const float*)d_in[26];
  const float* bc2 = (const float*)d_in[27];

  // workspace: xn/hn [128][512][128] f32 (33.5MB), en/he [512][512][128] f32 (134MB)
  float* xn = (float*)d_ws;
  float* en = xn + (size_t)128 * T_ * HN_;
  float* out = (float*)d_out;

  node_mlp_mfma_kernel<<<512, 512, 0, stream>>>(x_seq, Wn1, bn1, Wn2, bn2,
                                                Wg1, bg1, Wg2, bg2, xn);
  edge_mlp_mfma_kernel<<<512, 512, 0, stream>>>(ea, We1, be1, We2, be2,
                                                Wef1, bef1, Wef2, bef2, en);
  lstm_mfma_kernel<<<80, 512, 0, stream>>>(Wih_n, Whh_n, b_n,
                                           Wih_e, Whh_e, b_e, xn, en);
  classifier_mfma_kernel<<<256, 512, 0, stream>>>(xn, en, Wc1, bc1, Wc2, bc2, out);
}

// Round 8
// 779.545 us; speedup vs baseline: 1.0610x; 1.0610x over previous
//
#include <hip/hip_runtime.h>
#include <cstdint>

// Problem constants (B,T,N,E)=(32,512,4,16), NI=16, EI=8, HN=HE=128, MH=256, C=8
constexpr int T_  = 512;
constexpr int HN_ = 128;

#define DEVI __device__ __forceinline__

typedef __bf16 bf16x8 __attribute__((ext_vector_type(8)));
typedef __bf16 bf16x4 __attribute__((ext_vector_type(4)));
typedef float  f32x4  __attribute__((ext_vector_type(4)));

DEVI float sigf(float x) { return __builtin_amdgcn_rcpf(1.f + __expf(-x)); }
DEVI float tanh_fast(float x) {   // no clamp: exp handles +-inf correctly
  return 1.f - 2.f * __builtin_amdgcn_rcpf(1.f + __expf(2.f * x));
}

// ---- shared MFMA layer helpers (64-row tile, 128->128, wave w owns cols n)
DEVI void layer128_bf(const __bf16* __restrict__ src, __bf16* __restrict__ dst,
                      bf16x8 w0, bf16x8 w1, bf16x8 w2, bf16x8 w3,
                      float bv, int lm, int lh, int n)
{
  #pragma unroll
  for (int m = 0; m < 4; ++m) {
    const __bf16* sp = &src[(m*16 + lm)*136 + lh*8];
    const bf16x8 a0 = *reinterpret_cast<const bf16x8*>(sp);
    const bf16x8 a1 = *reinterpret_cast<const bf16x8*>(sp + 32);
    const bf16x8 a2 = *reinterpret_cast<const bf16x8*>(sp + 64);
    const bf16x8 a3 = *reinterpret_cast<const bf16x8*>(sp + 96);
    f32x4 acc = { bv, bv, bv, bv };
    acc = __builtin_amdgcn_mfma_f32_16x16x32_bf16(a0, w0, acc, 0, 0, 0);
    acc = __builtin_amdgcn_mfma_f32_16x16x32_bf16(a1, w1, acc, 0, 0, 0);
    acc = __builtin_amdgcn_mfma_f32_16x16x32_bf16(a2, w2, acc, 0, 0, 0);
    acc = __builtin_amdgcn_mfma_f32_16x16x32_bf16(a3, w3, acc, 0, 0, 0);
    #pragma unroll
    for (int r = 0; r < 4; ++r)
      dst[(m*16 + lh*4 + r)*136 + n] = (__bf16)fmaxf(acc[r], 0.f);
  }
}

DEVI void layer128_f32(const __bf16* __restrict__ src, float* __restrict__ dst,
                       bf16x8 w0, bf16x8 w1, bf16x8 w2, bf16x8 w3,
                       float bv, bool relu, int lm, int lh, int n)
{
  #pragma unroll
  for (int m = 0; m < 4; ++m) {
    const __bf16* sp = &src[(m*16 + lm)*136 + lh*8];
    const bf16x8 a0 = *reinterpret_cast<const bf16x8*>(sp);
    const bf16x8 a1 = *reinterpret_cast<const bf16x8*>(sp + 32);
    const bf16x8 a2 = *reinterpret_cast<const bf16x8*>(sp + 64);
    const bf16x8 a3 = *reinterpret_cast<const bf16x8*>(sp + 96);
    f32x4 acc = { bv, bv, bv, bv };
    acc = __builtin_amdgcn_mfma_f32_16x16x32_bf16(a0, w0, acc, 0, 0, 0);
    acc = __builtin_amdgcn_mfma_f32_16x16x32_bf16(a1, w1, acc, 0, 0, 0);
    acc = __builtin_amdgcn_mfma_f32_16x16x32_bf16(a2, w2, acc, 0, 0, 0);
    acc = __builtin_amdgcn_mfma_f32_16x16x32_bf16(a3, w3, acc, 0, 0, 0);
    #pragma unroll
    for (int r = 0; r < 4; ++r)
      dst[(m*16 + lh*4 + r)*132 + n] = relu ? fmaxf(acc[r], 0.f) : acc[r];
  }
}

// ---------------- K1: node MLP + 2 graph-conv layers (MFMA) -> xn (bf16)
__global__ __launch_bounds__(512, 4) void node_mlp_mfma_kernel(
    const float* __restrict__ x_seq,
    const float* __restrict__ Wn1, const float* __restrict__ bn1,
    const float* __restrict__ Wn2, const float* __restrict__ bn2,
    const float* __restrict__ Wg1, const float* __restrict__ bg1,
    const float* __restrict__ Wg2, const float* __restrict__ bg2,
    __bf16* __restrict__ xn)
{
  constexpr int P1 = 40;
  __shared__ __align__(16) __bf16 A1[64 * P1];
  __shared__ __align__(16) __bf16 Ab[64 * 136];
  __shared__ __align__(16) __bf16 Bb[64 * 136];
  __shared__ __align__(16) float  Yf[64 * 132];

  const int tid = threadIdx.x;
  const int w = tid >> 6, l = tid & 63, lm = l & 15, lh = l >> 4;
  const int n = w*16 + lm;

  bf16x8 w1, w2[4], w3[4], w4[4];
  const float b1 = bn1[n], b2 = bn2[n];
  #pragma unroll
  for (int j = 0; j < 8; ++j) {
    const int k = lh*8 + j;
    w1[j] = (k < 16) ? (__bf16)Wn1[k*128 + n] : (__bf16)0.f;
  }
  #pragma unroll
  for (int kt = 0; kt < 4; ++kt)
    #pragma unroll
    for (int j = 0; j < 8; ++j) {
      const int k = kt*32 + lh*8 + j;
      w2[kt][j] = (__bf16)Wn2[k*128 + n];
      w3[kt][j] = (__bf16)Wg1[k*128 + n];
      w4[kt][j] = (__bf16)Wg2[k*128 + n];
    }

  for (int i = tid; i < 64 * P1; i += 512) A1[i] = (__bf16)0.f;

  for (int g = blockIdx.x; g < 1024; g += 512) {
    #pragma unroll
    for (int it = 0; it < 2; ++it) {
      const int i = tid + it*512;
      A1[(i >> 4)*P1 + (i & 15)] = (__bf16)x_seq[(size_t)g*1024 + i];
    }
    __syncthreads();
    #pragma unroll
    for (int m = 0; m < 4; ++m) {
      const bf16x8 a = *reinterpret_cast<const bf16x8*>(&A1[(m*16+lm)*P1 + lh*8]);
      f32x4 acc = { b1, b1, b1, b1 };
      acc = __builtin_amdgcn_mfma_f32_16x16x32_bf16(a, w1, acc, 0, 0, 0);
      #pragma unroll
      for (int r = 0; r < 4; ++r)
        Ab[(m*16 + lh*4 + r)*136 + n] = (__bf16)fmaxf(acc[r], 0.f);
    }
    __syncthreads();
    layer128_bf(Ab, Bb, w2[0], w2[1], w2[2], w2[3], b2, lm, lh, n);   // L2
    __syncthreads();
    layer128_f32(Bb, Yf, w3[0], w3[1], w3[2], w3[3], 0.f, false, lm, lh, n); // G1
    __syncthreads();
    #pragma unroll
    for (int it = 0; it < 4; ++it) {
      const int idx = tid + it*512;
      const int q = idx >> 7, d = idx & 127;
      const float y0 = Yf[(q*4+0)*132 + d], y1 = Yf[(q*4+1)*132 + d];
      const float y2 = Yf[(q*4+2)*132 + d], y3 = Yf[(q*4+3)*132 + d];
      const float s = y0 + y1 + y2 + y3;
      const float bv = bg1[d];
      Ab[(q*4+0)*136 + d] = (__bf16)fmaxf((s + y0)*0.2f + bv, 0.f);
      Ab[(q*4+1)*136 + d] = (__bf16)fmaxf((s + y1)*0.2f + bv, 0.f);
      Ab[(q*4+2)*136 + d] = (__bf16)fmaxf((s + y2)*0.2f + bv, 0.f);
      Ab[(q*4+3)*136 + d] = (__bf16)fmaxf((s + y3)*0.2f + bv, 0.f);
    }
    __syncthreads();
    layer128_f32(Ab, Yf, w4[0], w4[1], w4[2], w4[3], 0.f, false, lm, lh, n); // G2
    __syncthreads();
    #pragma unroll
    for (int it = 0; it < 4; ++it) {
      const int idx = tid + it*512;
      const int q = idx >> 7, d = idx & 127;
      const int bt = g*16 + q, bb = bt >> 9, tt = bt & 511;
      const float y0 = Yf[(q*4+0)*132 + d], y1 = Yf[(q*4+1)*132 + d];
      const float y2 = Yf[(q*4+2)*132 + d], y3 = Yf[(q*4+3)*132 + d];
      const float s = y0 + y1 + y2 + y3;
      const float bv = bg2[d];
      xn[((size_t)(bb*4+0)*T_ + tt)*HN_ + d] = (__bf16)fmaxf((s + y0)*0.2f + bv, 0.f);
      xn[((size_t)(bb*4+1)*T_ + tt)*HN_ + d] = (__bf16)fmaxf((s + y1)*0.2f + bv, 0.f);
      xn[((size_t)(bb*4+2)*T_ + tt)*HN_ + d] = (__bf16)fmaxf((s + y2)*0.2f + bv, 0.f);
      xn[((size_t)(bb*4+3)*T_ + tt)*HN_ + d] = (__bf16)fmaxf((s + y3)*0.2f + bv, 0.f);
    }
    __syncthreads();
  }
}

// ---------------- K2: edge MLP (4 layers, MFMA) -> en (bf16)
__global__ __launch_bounds__(512, 4) void edge_mlp_mfma_kernel(
    const float* __restrict__ ea,
    const float* __restrict__ We1, const float* __restrict__ be1,
    const float* __restrict__ We2, const float* __restrict__ be2,
    const float* __restrict__ Wef1, const float* __restrict__ bef1,
    const float* __restrict__ Wef2, const float* __restrict__ bef2,
    __bf16* __restrict__ en)
{
  constexpr int P1 = 40;
  __shared__ __align__(16) __bf16 A1[64 * P1];
  __shared__ __align__(16) __bf16 Ab[64 * 136];
  __shared__ __align__(16) __bf16 Bb[64 * 136];
  __shared__ __align__(16) float  Of[64 * 132];

  const int tid = threadIdx.x;
  const int w = tid >> 6, l = tid & 63, lm = l & 15, lh = l >> 4;
  const int n = w*16 + lm;

  bf16x8 w1, w2[4], w3[4], w4[4];
  const float b1 = be1[n], b2 = be2[n], b3 = bef1[n], b4 = bef2[n];
  #pragma unroll
  for (int j = 0; j < 8; ++j) {
    const int k = lh*8 + j;
    w1[j] = (k < 8) ? (__bf16)We1[k*128 + n] : (__bf16)0.f;
  }
  #pragma unroll
  for (int kt = 0; kt < 4; ++kt)
    #pragma unroll
    for (int j = 0; j < 8; ++j) {
      const int k = kt*32 + lh*8 + j;
      w2[kt][j] = (__bf16)We2[k*128 + n];
      w3[kt][j] = (__bf16)Wef1[k*128 + n];
      w4[kt][j] = (__bf16)Wef2[k*128 + n];
    }

  for (int i = tid; i < 64 * P1; i += 512) A1[i] = (__bf16)0.f;

  for (int g = blockIdx.x; g < 4096; g += 512) {
    A1[(tid >> 3)*P1 + (tid & 7)] = (__bf16)ea[(size_t)g*512 + tid];
    __syncthreads();
    #pragma unroll
    for (int m = 0; m < 4; ++m) {
      const bf16x8 a = *reinterpret_cast<const bf16x8*>(&A1[(m*16+lm)*P1 + lh*8]);
      f32x4 acc = { b1, b1, b1, b1 };
      acc = __builtin_amdgcn_mfma_f32_16x16x32_bf16(a, w1, acc, 0, 0, 0);
      #pragma unroll
      for (int r = 0; r < 4; ++r)
        Ab[(m*16 + lh*4 + r)*136 + n] = (__bf16)fmaxf(acc[r], 0.f);
    }
    __syncthreads();
    layer128_bf(Ab, Bb, w2[0], w2[1], w2[2], w2[3], b2, lm, lh, n);          // L2
    __syncthreads();
    layer128_bf(Bb, Ab, w3[0], w3[1], w3[2], w3[3], b3, lm, lh, n);          // L3
    __syncthreads();
    layer128_f32(Ab, Of, w4[0], w4[1], w4[2], w4[3], b4, true, lm, lh, n);   // L4
    __syncthreads();
    #pragma unroll
    for (int i = 0; i < 4; ++i) {
      const int fi = tid + i*512;
      const int row = fi >> 5, c4 = fi & 31;
      const int q = row >> 4, e = row & 15;
      const int bt = g*4 + q, bb = bt >> 9, tt = bt & 511;
      const float4 v = *reinterpret_cast<const float4*>(&Of[row*132 + c4*4]);
      bf16x4 pk;
      pk[0]=(__bf16)v.x; pk[1]=(__bf16)v.y; pk[2]=(__bf16)v.z; pk[3]=(__bf16)v.w;
      *reinterpret_cast<bf16x4*>(
          &en[((size_t)(bb*16+e)*T_ + tt)*HN_ + c4*4]) = pk;
    }
    __syncthreads();
  }
}

// ---------------- K3: LSTM v3 — LDS-minimal recurrence
// 40 blocks (8 node + 32 edge), 16 seqs/block, 8 waves. xh global is bf16.
// x B-fragments: global->VGPR, prefetched 2 steps ahead (VMEM pipe; no LDS).
// Weights A-fragments gate-interleaved (row m -> gate m&3, dimsub m>>2) so
// each lane's 4 accumulators are {i,f,g,o} of one (seq,dim): gates fully
// in-register, no cross-lane exchange. Only LDS: h ring [16 slots][16 seq]
// [128 bf16], 16B-unit XOR swizzle (unit ^ (seq&7)) -> conflict-free b128
// reads. Ring flushed to global (bf16) once per 16 steps.
__global__ __launch_bounds__(512, 2) void lstm_mfma_kernel(
    const float* __restrict__ Wih_n, const float* __restrict__ Whh_n,
    const float* __restrict__ b_n,
    const float* __restrict__ Wih_e, const float* __restrict__ Whh_e,
    const float* __restrict__ b_e,
    __bf16* __restrict__ xn, __bf16* __restrict__ en)
{
  __shared__ __align__(16) __bf16 ring[16 * 16 * 128];   // 64 KiB

  const bool is_node = (int)blockIdx.x < 8;
  const int  bidx    = is_node ? blockIdx.x : ((int)blockIdx.x - 8);
  const float* __restrict__ Wih  = is_node ? Wih_n : Wih_e;
  const float* __restrict__ Whh  = is_node ? Whh_n : Whh_e;
  const float* __restrict__ bias = is_node ? b_n   : b_e;
  __bf16* __restrict__ xh = (is_node ? xn : en) + (size_t)bidx * 16 * (T_ * HN_);

  const int tid = threadIdx.x;
  const int w   = tid >> 6;       // wave 0..7 -> dims [16w,16w+16)
  const int l   = tid & 63;
  const int lm  = l & 15;         // A row within tile / B col (seq)
  const int lh  = l >> 4;

  // A fragments, gate-interleaved: tile nt, row m=lm -> gate lm&3,
  // dim = w*16 + nt*4 + (lm>>2); k = kt*32 + lh*8 + j.
  bf16x8 wih_f[4][4], whh_f[4][4];
  f32x4  bias_v[4];
  #pragma unroll
  for (int nt = 0; nt < 4; ++nt) {
    const int d   = w*16 + nt*4 + lh;         // dim for THIS lane's accs
    bias_v[nt][0] = bias[0*128 + d];
    bias_v[nt][1] = bias[1*128 + d];
    bias_v[nt][2] = bias[2*128 + d];
    bias_v[nt][3] = bias[3*128 + d];
    const int col = (lm & 3)*128 + w*16 + nt*4 + (lm >> 2);
    #pragma unroll
    for (int kt = 0; kt < 4; ++kt)
      #pragma unroll
      for (int j = 0; j < 8; ++j) {
        const int k = kt*32 + lh*8 + j;
        wih_f[nt][kt][j] = (__bf16)Wih[k*512 + col];
        whh_f[nt][kt][j] = (__bf16)Whh[k*512 + col];
      }
  }

  // zero ring slot 15 (h_{-1} = 0)
  {
    bf16x4 z; z[0]=z[1]=z[2]=z[3]=(__bf16)0.f;
    *reinterpret_cast<bf16x4*>(&ring[15*2048 + tid*4]) = z;
  }
  __syncthreads();

  const size_t seqStride = (size_t)T_ * HN_;
  const __bf16* __restrict__ xseq = xh + (size_t)lm * seqStride;

  // prologue: x(0) -> accsX
  f32x4 accsX[4];
  {
    bf16x8 bx[4];
    #pragma unroll
    for (int kt = 0; kt < 4; ++kt)
      bx[kt] = *reinterpret_cast<const bf16x8*>(&xseq[kt*32 + lh*8]);
    #pragma unroll
    for (int nt = 0; nt < 4; ++nt) {
      accsX[nt] = bias_v[nt];
      #pragma unroll
      for (int kt = 0; kt < 4; ++kt)
        accsX[nt] = __builtin_amdgcn_mfma_f32_16x16x32_bf16(wih_f[nt][kt], bx[kt], accsX[nt], 0, 0, 0);
    }
  }
  // prefetch x(1)
  bf16x8 bxO[4], bxE[4];
  #pragma unroll
  for (int kt = 0; kt < 4; ++kt)
    bxO[kt] = *reinterpret_cast<const bf16x8*>(&xseq[(size_t)1*HN_ + kt*32 + lh*8]);

  float c[4] = {0.f, 0.f, 0.f, 0.f};

  #pragma unroll 2
  for (int t = 0; t < T_; ++t) {
    // issue x prefetch for t+2 into the buffer not consumed this step
    bf16x8* bxLoad = (t & 1) ? bxO : bxE;
    bf16x8* bxUse  = (t & 1) ? bxE : bxO;   // holds x(t+1)
    {
      const int tp = (t + 2 < T_) ? t + 2 : T_ - 1;
      #pragma unroll
      for (int kt = 0; kt < 4; ++kt)
        bxLoad[kt] = *reinterpret_cast<const bf16x8*>(
            &xseq[(size_t)tp*HN_ + kt*32 + lh*8]);
    }

    // h_{t-1} fragments from ring slot (t+15)&15
    const int rbase = ((t + 15) & 15)*2048 + lm*128;
    bf16x8 bh[4];
    #pragma unroll
    for (int kt = 0; kt < 4; ++kt)
      bh[kt] = *reinterpret_cast<const bf16x8*>(
          &ring[rbase + (((kt*4 + lh) ^ (lm & 7)) << 3)]);

    // z = accsX (bias + x part) + Whh^T @ h
    #pragma unroll
    for (int nt = 0; nt < 4; ++nt)
      #pragma unroll
      for (int kt = 0; kt < 4; ++kt)
        accsX[nt] = __builtin_amdgcn_mfma_f32_16x16x32_bf16(whh_f[nt][kt], bh[kt], accsX[nt], 0, 0, 0);

    // gates fully in-register; write h to ring slot t&15 (swizzled b16)
    const int wbase = (t & 15)*2048 + lm*128;
    #pragma unroll
    for (int nt = 0; nt < 4; ++nt) {
      const float zi = accsX[nt][0], zf = accsX[nt][1];
      const float zg = accsX[nt][2], zo = accsX[nt][3];
      c[nt] = sigf(zf)*c[nt] + sigf(zi)*tanh_fast(zg);
      const float h = sigf(zo)*tanh_fast(c[nt]);
      const int up = (2*w + (nt >> 1)) ^ (lm & 7);
      ring[wbase + up*8 + (nt & 1)*4 + lh] = (__bf16)h;
    }

    // build accsX for t+1 (bias + x part) — off the recurrence path
    #pragma unroll
    for (int nt = 0; nt < 4; ++nt) {
      accsX[nt] = bias_v[nt];
      #pragma unroll
      for (int kt = 0; kt < 4; ++kt)
        accsX[nt] = __builtin_amdgcn_mfma_f32_16x16x32_bf16(wih_f[nt][kt], bxUse[kt], accsX[nt], 0, 0, 0);
    }
    __syncthreads();

    if ((t & 15) == 15) {   // bulk flush slots 0..15 = steps t-15..t
      const int tb = t - 15;
      #pragma unroll
      for (int i = 0; i < 8; ++i) {
        const int uf = tid + i*512;
        const int tl = uf >> 8, sq = (uf >> 4) & 15, us = uf & 15;
        const int ulog = us ^ (sq & 7);
        const bf16x8 v = *reinterpret_cast<const bf16x8*>(
            &ring[tl*2048 + sq*128 + us*8]);
        *reinterpret_cast<bf16x8*>(
            &xh[(size_t)sq*seqStride + (size_t)(tb + tl)*HN_ + ulog*8]) = v;
      }
      __syncthreads();
    }
  }
}

// ---------------- K4: MFMA gather + classifier (384 -> 256 -> 8), bf16 in
__global__ __launch_bounds__(512, 1) void classifier_mfma_kernel(
    const __bf16* __restrict__ hn, const __bf16* __restrict__ he,
    const float* __restrict__ Wc1, const float* __restrict__ bc1,
    const float* __restrict__ Wc2, const float* __restrict__ bc2,
    float* __restrict__ out)
{
  constexpr int HP = 136;
  constexpr int DP = 264;
  __shared__ __align__(16) __bf16 hn_l[32 * HP];
  __shared__ __align__(16) __bf16 he_l[128 * HP];
  __shared__ __align__(16) __bf16 hid_l[128 * DP];

  const int tid = threadIdx.x;
  const int w   = tid >> 6;
  const int l   = tid & 63;
  const int lm  = l & 15;
  const int lh  = l >> 4;

  bf16x8 wb[2][12];
  float  bcol[2];
  #pragma unroll
  for (int jt = 0; jt < 2; ++jt) {
    const int j = w*32 + jt*16 + lm;
    bcol[jt] = bc1[j];
    #pragma unroll
    for (int kt = 0; kt < 12; ++kt)
      #pragma unroll
      for (int i = 0; i < 8; ++i)
        wb[jt][kt][i] = (__bf16)Wc1[(kt*32 + lh*8 + i)*256 + j];
  }
  bf16x8 wc2f[8];
  const float bc2v = (lm < 8) ? bc2[lm] : 0.f;
  #pragma unroll
  for (int kt = 0; kt < 8; ++kt)
    #pragma unroll
    for (int i = 0; i < 8; ++i)
      wc2f[kt][i] = (lm < 8) ? (__bf16)Wc2[(kt*32 + lh*8 + i)*8 + lm] : (__bf16)0.f;

  for (int g = blockIdx.x; g < 2048; g += 256) {
    const int b  = g >> 6;
    const int t0 = (g & 63) * 8;

    // he: 16 e x 8 t x 128 = 2048 bf16x8 units
    for (int u = tid; u < 2048; u += 512) {
      const int e = u >> 7, rem = u & 127;
      const int tt = rem >> 4, k = (rem & 15)*8;
      const bf16x8 v = *reinterpret_cast<const bf16x8*>(
          &he[((size_t)(b*16+e)*T_ + t0 + tt)*HN_ + k]);
      *reinterpret_cast<bf16x8*>(&he_l[(tt*16 + e)*HP + k]) = v;
    }
    // hn: 4 n x 8 t x 128 = 512 bf16x8 units
    for (int u = tid; u < 512; u += 512) {
      const int n = u >> 7, rem = u & 127;
      const int tt = rem >> 4, k = (rem & 15)*8;
      const bf16x8 v = *reinterpret_cast<const bf16x8*>(
          &hn[((size_t)(b*4+n)*T_ + t0 + tt)*HN_ + k]);
      *reinterpret_cast<bf16x8*>(&hn_l[(tt*4 + n)*HP + k]) = v;
    }
    __syncthreads();

    for (int tt = 0; tt < 8; ++tt) {
      bf16x8 af[12];
      #pragma unroll
      for (int kt = 0; kt < 4; ++kt)
        af[kt] = *reinterpret_cast<const bf16x8*>(
            &hn_l[(tt*4 + (lm>>2))*HP + kt*32 + lh*8]);
      #pragma unroll
      for (int kt = 0; kt < 4; ++kt)
        af[4+kt] = *reinterpret_cast<const bf16x8*>(
            &hn_l[(tt*4 + (lm&3))*HP + kt*32 + lh*8]);
      #pragma unroll
      for (int kt = 0; kt < 4; ++kt)
        af[8+kt] = *reinterpret_cast<const bf16x8*>(
            &he_l[(tt*16 + lm)*HP + kt*32 + lh*8]);
      #pragma unroll
      for (int jt = 0; jt < 2; ++jt) {
        f32x4 acc = { bcol[jt], bcol[jt], bcol[jt], bcol[jt] };
        #pragma unroll
        for (int kt = 0; kt < 12; ++kt)
          acc = __builtin_amdgcn_mfma_f32_16x16x32_bf16(af[kt], wb[jt][kt], acc, 0, 0, 0);
        #pragma unroll
        for (int r = 0; r < 4; ++r)
          hid_l[(tt*16 + lh*4 + r)*DP + (w*2 + jt)*16 + lm] = (__bf16)fmaxf(acc[r], 0.f);
      }
    }
    __syncthreads();

    {
      const int tt = w;
      f32x4 acc = { bc2v, bc2v, bc2v, bc2v };
      #pragma unroll
      for (int kt = 0; kt < 8; ++kt) {
        const bf16x8 a = *reinterpret_cast<const bf16x8*>(
            &hid_l[(tt*16 + lm)*DP + kt*32 + lh*8]);
        acc = __builtin_amdgcn_mfma_f32_16x16x32_bf16(a, wc2f[kt], acc, 0, 0, 0);
      }
      if (lm < 8) {
        const size_t bt = (size_t)b*T_ + t0 + tt;
        #pragma unroll
        for (int r = 0; r < 4; ++r)
          out[(bt*16 + lh*4 + r)*8 + lm] = acc[r];
      }
    }
    __syncthreads();
  }
}

extern "C" void kernel_launch(void* const* d_in, const int* in_sizes, int n_in,
                              void* d_out, int out_size, void* d_ws, size_t ws_size,
                              hipStream_t stream) {
  (void)in_sizes; (void)n_in; (void)out_size; (void)ws_size;
  const float* x_seq = (const float*)d_in[0];
  const float* ea    = (const float*)d_in[1];
  const float* Wn1 = (const float*)d_in[2];
  const float* bn1 = (const float*)d_in[3];
  const float* Wn2 = (const float*)d_in[4];
  const float* bn2 = (const float*)d_in[5];
  const float* We1 = (const float*)d_in[6];
  const float* be1 = (const float*)d_in[7];
  const float* We2 = (const float*)d_in[8];
  const float* be2 = (const float*)d_in[9];
  const float* Wg1 = (const float*)d_in[10];
  const float* bg1 = (const float*)d_in[11];
  const float* Wg2 = (const float*)d_in[12];
  const float* bg2 = (const float*)d_in[13];
  const float* Wef1 = (const float*)d_in[14];
  const float* bef1 = (const float*)d_in[15];
  const float* Wef2 = (const float*)d_in[16];
  const float* bef2 = (const float*)d_in[17];
  const float* Wih_n = (const float*)d_in[18];
  const float* Whh_n = (const float*)d_in[19];
  const float* b_n   = (const float*)d_in[20];
  const float* Wih_e = (const float*)d_in[21];
  const float* Whh_e = (const float*)d_in[22];
  const float* b_e   = (const float*)d_in[23];
  const float* Wc1 = (const float*)d_in[24];
  const float* bc1 = (const float*)d_in[25];
  const float* Wc2 = (const float*)d_in[26];
  const float* bc2 = (const float*)d_in[27];

  // workspace (bf16): xn/hn [128][512][128] (16.8MB), en/he [512][512][128] (67MB)
  __bf16* xn = (__bf16*)d_ws;
  __bf16* en = xn + (size_t)128 * T_ * HN_;
  float* out = (float*)d_out;

  node_mlp_mfma_kernel<<<512, 512, 0, stream>>>(x_seq, Wn1, bn1, Wn2, bn2,
                                                Wg1, bg1, Wg2, bg2, xn);
  edge_mlp_mfma_kernel<<<512, 512, 0, stream>>>(ea, We1, be1, We2, be2,
                                                Wef1, bef1, Wef2, bef2, en);
  // 8 node blocks (128 seqs) + 32 edge blocks (512 seqs), 16 seqs each
  lstm_mfma_kernel<<<40, 512, 0, stream>>>(Wih_n, Whh_n, b_n,
                                           Wih_e, Whh_e, b_e, xn, en);
  classifier_mfma_kernel<<<256, 512, 0, stream>>>(xn, en, Wc1, bc1, Wc2, bc2, out);
}

// Round 9
// 774.345 us; speedup vs baseline: 1.0681x; 1.0067x over previous
//
#include <hip/hip_runtime.h>
#include <cstdint>

// Problem constants (B,T,N,E)=(32,512,4,16), NI=16, EI=8, HN=HE=128, MH=256, C=8
constexpr int T_  = 512;
constexpr int HN_ = 128;

#define DEVI __device__ __forceinline__

typedef __bf16 bf16x8 __attribute__((ext_vector_type(8)));
typedef __bf16 bf16x4 __attribute__((ext_vector_type(4)));
typedef float  f32x4  __attribute__((ext_vector_type(4)));

DEVI float sigf(float x) { return __builtin_amdgcn_rcpf(1.f + __expf(-x)); }
DEVI float tanh_fast(float x) {   // no clamp: exp handles +-inf correctly
  return 1.f - 2.f * __builtin_amdgcn_rcpf(1.f + __expf(2.f * x));
}

// ---- shared MFMA layer helpers (64-row tile, 128->128, wave w owns cols n)
DEVI void layer128_bf(const __bf16* __restrict__ src, __bf16* __restrict__ dst,
                      bf16x8 w0, bf16x8 w1, bf16x8 w2, bf16x8 w3,
                      float bv, int lm, int lh, int n)
{
  #pragma unroll
  for (int m = 0; m < 4; ++m) {
    const __bf16* sp = &src[(m*16 + lm)*136 + lh*8];
    const bf16x8 a0 = *reinterpret_cast<const bf16x8*>(sp);
    const bf16x8 a1 = *reinterpret_cast<const bf16x8*>(sp + 32);
    const bf16x8 a2 = *reinterpret_cast<const bf16x8*>(sp + 64);
    const bf16x8 a3 = *reinterpret_cast<const bf16x8*>(sp + 96);
    f32x4 acc = { bv, bv, bv, bv };
    acc = __builtin_amdgcn_mfma_f32_16x16x32_bf16(a0, w0, acc, 0, 0, 0);
    acc = __builtin_amdgcn_mfma_f32_16x16x32_bf16(a1, w1, acc, 0, 0, 0);
    acc = __builtin_amdgcn_mfma_f32_16x16x32_bf16(a2, w2, acc, 0, 0, 0);
    acc = __builtin_amdgcn_mfma_f32_16x16x32_bf16(a3, w3, acc, 0, 0, 0);
    #pragma unroll
    for (int r = 0; r < 4; ++r)
      dst[(m*16 + lh*4 + r)*136 + n] = (__bf16)fmaxf(acc[r], 0.f);
  }
}

DEVI void layer128_f32(const __bf16* __restrict__ src, float* __restrict__ dst,
                       bf16x8 w0, bf16x8 w1, bf16x8 w2, bf16x8 w3,
                       float bv, bool relu, int lm, int lh, int n)
{
  #pragma unroll
  for (int m = 0; m < 4; ++m) {
    const __bf16* sp = &src[(m*16 + lm)*136 + lh*8];
    const bf16x8 a0 = *reinterpret_cast<const bf16x8*>(sp);
    const bf16x8 a1 = *reinterpret_cast<const bf16x8*>(sp + 32);
    const bf16x8 a2 = *reinterpret_cast<const bf16x8*>(sp + 64);
    const bf16x8 a3 = *reinterpret_cast<const bf16x8*>(sp + 96);
    f32x4 acc = { bv, bv, bv, bv };
    acc = __builtin_amdgcn_mfma_f32_16x16x32_bf16(a0, w0, acc, 0, 0, 0);
    acc = __builtin_amdgcn_mfma_f32_16x16x32_bf16(a1, w1, acc, 0, 0, 0);
    acc = __builtin_amdgcn_mfma_f32_16x16x32_bf16(a2, w2, acc, 0, 0, 0);
    acc = __builtin_amdgcn_mfma_f32_16x16x32_bf16(a3, w3, acc, 0, 0, 0);
    #pragma unroll
    for (int r = 0; r < 4; ++r)
      dst[(m*16 + lh*4 + r)*132 + n] = relu ? fmaxf(acc[r], 0.f) : acc[r];
  }
}

// ---------------- K1: node MLP + 2 graph-conv layers (MFMA) -> xn (bf16)
__global__ __launch_bounds__(512, 4) void node_mlp_mfma_kernel(
    const float* __restrict__ x_seq,
    const float* __restrict__ Wn1, const float* __restrict__ bn1,
    const float* __restrict__ Wn2, const float* __restrict__ bn2,
    const float* __restrict__ Wg1, const float* __restrict__ bg1,
    const float* __restrict__ Wg2, const float* __restrict__ bg2,
    __bf16* __restrict__ xn)
{
  constexpr int P1 = 40;
  __shared__ __align__(16) __bf16 A1[64 * P1];
  __shared__ __align__(16) __bf16 Ab[64 * 136];
  __shared__ __align__(16) __bf16 Bb[64 * 136];
  __shared__ __align__(16) float  Yf[64 * 132];

  const int tid = threadIdx.x;
  const int w = tid >> 6, l = tid & 63, lm = l & 15, lh = l >> 4;
  const int n = w*16 + lm;

  bf16x8 w1, w2[4], w3[4], w4[4];
  const float b1 = bn1[n], b2 = bn2[n];
  #pragma unroll
  for (int j = 0; j < 8; ++j) {
    const int k = lh*8 + j;
    w1[j] = (k < 16) ? (__bf16)Wn1[k*128 + n] : (__bf16)0.f;
  }
  #pragma unroll
  for (int kt = 0; kt < 4; ++kt)
    #pragma unroll
    for (int j = 0; j < 8; ++j) {
      const int k = kt*32 + lh*8 + j;
      w2[kt][j] = (__bf16)Wn2[k*128 + n];
      w3[kt][j] = (__bf16)Wg1[k*128 + n];
      w4[kt][j] = (__bf16)Wg2[k*128 + n];
    }

  for (int i = tid; i < 64 * P1; i += 512) A1[i] = (__bf16)0.f;

  for (int g = blockIdx.x; g < 1024; g += 512) {
    #pragma unroll
    for (int it = 0; it < 2; ++it) {
      const int i = tid + it*512;
      A1[(i >> 4)*P1 + (i & 15)] = (__bf16)x_seq[(size_t)g*1024 + i];
    }
    __syncthreads();
    #pragma unroll
    for (int m = 0; m < 4; ++m) {
      const bf16x8 a = *reinterpret_cast<const bf16x8*>(&A1[(m*16+lm)*P1 + lh*8]);
      f32x4 acc = { b1, b1, b1, b1 };
      acc = __builtin_amdgcn_mfma_f32_16x16x32_bf16(a, w1, acc, 0, 0, 0);
      #pragma unroll
      for (int r = 0; r < 4; ++r)
        Ab[(m*16 + lh*4 + r)*136 + n] = (__bf16)fmaxf(acc[r], 0.f);
    }
    __syncthreads();
    layer128_bf(Ab, Bb, w2[0], w2[1], w2[2], w2[3], b2, lm, lh, n);   // L2
    __syncthreads();
    layer128_f32(Bb, Yf, w3[0], w3[1], w3[2], w3[3], 0.f, false, lm, lh, n); // G1
    __syncthreads();
    #pragma unroll
    for (int it = 0; it < 4; ++it) {
      const int idx = tid + it*512;
      const int q = idx >> 7, d = idx & 127;
      const float y0 = Yf[(q*4+0)*132 + d], y1 = Yf[(q*4+1)*132 + d];
      const float y2 = Yf[(q*4+2)*132 + d], y3 = Yf[(q*4+3)*132 + d];
      const float s = y0 + y1 + y2 + y3;
      const float bv = bg1[d];
      Ab[(q*4+0)*136 + d] = (__bf16)fmaxf((s + y0)*0.2f + bv, 0.f);
      Ab[(q*4+1)*136 + d] = (__bf16)fmaxf((s + y1)*0.2f + bv, 0.f);
      Ab[(q*4+2)*136 + d] = (__bf16)fmaxf((s + y2)*0.2f + bv, 0.f);
      Ab[(q*4+3)*136 + d] = (__bf16)fmaxf((s + y3)*0.2f + bv, 0.f);
    }
    __syncthreads();
    layer128_f32(Ab, Yf, w4[0], w4[1], w4[2], w4[3], 0.f, false, lm, lh, n); // G2
    __syncthreads();
    #pragma unroll
    for (int it = 0; it < 4; ++it) {
      const int idx = tid + it*512;
      const int q = idx >> 7, d = idx & 127;
      const int bt = g*16 + q, bb = bt >> 9, tt = bt & 511;
      const float y0 = Yf[(q*4+0)*132 + d], y1 = Yf[(q*4+1)*132 + d];
      const float y2 = Yf[(q*4+2)*132 + d], y3 = Yf[(q*4+3)*132 + d];
      const float s = y0 + y1 + y2 + y3;
      const float bv = bg2[d];
      xn[((size_t)(bb*4+0)*T_ + tt)*HN_ + d] = (__bf16)fmaxf((s + y0)*0.2f + bv, 0.f);
      xn[((size_t)(bb*4+1)*T_ + tt)*HN_ + d] = (__bf16)fmaxf((s + y1)*0.2f + bv, 0.f);
      xn[((size_t)(bb*4+2)*T_ + tt)*HN_ + d] = (__bf16)fmaxf((s + y2)*0.2f + bv, 0.f);
      xn[((size_t)(bb*4+3)*T_ + tt)*HN_ + d] = (__bf16)fmaxf((s + y3)*0.2f + bv, 0.f);
    }
    __syncthreads();
  }
}

// ---------------- K2: edge MLP (4 layers, MFMA) -> en (bf16)
__global__ __launch_bounds__(512, 4) void edge_mlp_mfma_kernel(
    const float* __restrict__ ea,
    const float* __restrict__ We1, const float* __restrict__ be1,
    const float* __restrict__ We2, const float* __restrict__ be2,
    const float* __restrict__ Wef1, const float* __restrict__ bef1,
    const float* __restrict__ Wef2, const float* __restrict__ bef2,
    __bf16* __restrict__ en)
{
  constexpr int P1 = 40;
  __shared__ __align__(16) __bf16 A1[64 * P1];
  __shared__ __align__(16) __bf16 Ab[64 * 136];
  __shared__ __align__(16) __bf16 Bb[64 * 136];
  __shared__ __align__(16) float  Of[64 * 132];

  const int tid = threadIdx.x;
  const int w = tid >> 6, l = tid & 63, lm = l & 15, lh = l >> 4;
  const int n = w*16 + lm;

  bf16x8 w1, w2[4], w3[4], w4[4];
  const float b1 = be1[n], b2 = be2[n], b3 = bef1[n], b4 = bef2[n];
  #pragma unroll
  for (int j = 0; j < 8; ++j) {
    const int k = lh*8 + j;
    w1[j] = (k < 8) ? (__bf16)We1[k*128 + n] : (__bf16)0.f;
  }
  #pragma unroll
  for (int kt = 0; kt < 4; ++kt)
    #pragma unroll
    for (int j = 0; j < 8; ++j) {
      const int k = kt*32 + lh*8 + j;
      w2[kt][j] = (__bf16)We2[k*128 + n];
      w3[kt][j] = (__bf16)Wef1[k*128 + n];
      w4[kt][j] = (__bf16)Wef2[k*128 + n];
    }

  for (int i = tid; i < 64 * P1; i += 512) A1[i] = (__bf16)0.f;

  for (int g = blockIdx.x; g < 4096; g += 512) {
    A1[(tid >> 3)*P1 + (tid & 7)] = (__bf16)ea[(size_t)g*512 + tid];
    __syncthreads();
    #pragma unroll
    for (int m = 0; m < 4; ++m) {
      const bf16x8 a = *reinterpret_cast<const bf16x8*>(&A1[(m*16+lm)*P1 + lh*8]);
      f32x4 acc = { b1, b1, b1, b1 };
      acc = __builtin_amdgcn_mfma_f32_16x16x32_bf16(a, w1, acc, 0, 0, 0);
      #pragma unroll
      for (int r = 0; r < 4; ++r)
        Ab[(m*16 + lh*4 + r)*136 + n] = (__bf16)fmaxf(acc[r], 0.f);
    }
    __syncthreads();
    layer128_bf(Ab, Bb, w2[0], w2[1], w2[2], w2[3], b2, lm, lh, n);          // L2
    __syncthreads();
    layer128_bf(Bb, Ab, w3[0], w3[1], w3[2], w3[3], b3, lm, lh, n);          // L3
    __syncthreads();
    layer128_f32(Ab, Of, w4[0], w4[1], w4[2], w4[3], b4, true, lm, lh, n);   // L4
    __syncthreads();
    #pragma unroll
    for (int i = 0; i < 4; ++i) {
      const int fi = tid + i*512;
      const int row = fi >> 5, c4 = fi & 31;
      const int q = row >> 4, e = row & 15;
      const int bt = g*4 + q, bb = bt >> 9, tt = bt & 511;
      const float4 v = *reinterpret_cast<const float4*>(&Of[row*132 + c4*4]);
      bf16x4 pk;
      pk[0]=(__bf16)v.x; pk[1]=(__bf16)v.y; pk[2]=(__bf16)v.z; pk[3]=(__bf16)v.w;
      *reinterpret_cast<bf16x4*>(
          &en[((size_t)(bb*16+e)*T_ + tt)*HN_ + c4*4]) = pk;
    }
    __syncthreads();
  }
}

// ---------------- K3: LSTM v4 — steady-state steps touch LDS only
// 40 blocks, 16 seqs/block, 8 waves. x chunk (16 steps, 64KB) staged via
// global_load_lds at chunk boundaries (ONE vmcnt drain per 16 steps, not per
// step — the per-step barrier previously drained an in-flight HBM prefetch).
// Source pre-swizzled (T21): LDS linear dest, global k-unit = v ^ (seq&7);
// reads apply the same XOR. Gates in-register (gate-interleaved A fragments).
// h ring [16 slots][16 seq][128 bf16], unit-XOR swizzled, flushed per chunk.
__global__ __launch_bounds__(512, 1) void lstm_mfma_kernel(
    const float* __restrict__ Wih_n, const float* __restrict__ Whh_n,
    const float* __restrict__ b_n,
    const float* __restrict__ Wih_e, const float* __restrict__ Whh_e,
    const float* __restrict__ b_e,
    __bf16* __restrict__ xn, __bf16* __restrict__ en)
{
  __shared__ __align__(16) __bf16 x_c[16 * 2048];   // 64 KiB [seq][tl][unit]
  __shared__ __align__(16) __bf16 ring[16 * 2048];  // 64 KiB [slot][seq][unit]

  const bool is_node = (int)blockIdx.x < 8;
  const int  bidx    = is_node ? blockIdx.x : ((int)blockIdx.x - 8);
  const float* __restrict__ Wih  = is_node ? Wih_n : Wih_e;
  const float* __restrict__ Whh  = is_node ? Whh_n : Whh_e;
  const float* __restrict__ bias = is_node ? b_n   : b_e;
  __bf16* __restrict__ xh = (is_node ? xn : en) + (size_t)bidx * 16 * (T_ * HN_);

  const int tid = threadIdx.x;
  const int w   = tid >> 6;       // wave 0..7 -> dims [16w,16w+16)
  const int l   = tid & 63;
  const int lm  = l & 15;         // A row within tile / B col (seq)
  const int lh  = l >> 4;

  // A fragments, gate-interleaved: tile nt, row m=lm -> gate lm&3,
  // dim = w*16 + nt*4 + (lm>>2); k = kt*32 + lh*8 + j.
  bf16x8 wih_f[4][4], whh_f[4][4];
  f32x4  bias_v[4];
  #pragma unroll
  for (int nt = 0; nt < 4; ++nt) {
    const int d   = w*16 + nt*4 + lh;         // dim for THIS lane's accs
    bias_v[nt][0] = bias[0*128 + d];
    bias_v[nt][1] = bias[1*128 + d];
    bias_v[nt][2] = bias[2*128 + d];
    bias_v[nt][3] = bias[3*128 + d];
    const int col = (lm & 3)*128 + w*16 + nt*4 + (lm >> 2);
    #pragma unroll
    for (int kt = 0; kt < 4; ++kt)
      #pragma unroll
      for (int j = 0; j < 8; ++j) {
        const int k = kt*32 + lh*8 + j;
        wih_f[nt][kt][j] = (__bf16)Wih[k*512 + col];
        whh_f[nt][kt][j] = (__bf16)Whh[k*512 + col];
      }
  }

  // zero ring slot 15 (h_{-1} = 0)
  {
    bf16x4 z; z[0]=z[1]=z[2]=z[3]=(__bf16)0.f;
    *reinterpret_cast<bf16x4*>(&ring[15*2048 + tid*4]) = z;
  }

  const size_t seqStride = (size_t)T_ * HN_;
  // per-lane swizzled fragment offsets (bf16 elems within a 256B row)
  int fsw[4];
  #pragma unroll
  for (int kt = 0; kt < 4; ++kt) fsw[kt] = (((kt*4 + lh) ^ (lm & 7)) << 3);

  float c[4] = {0.f, 0.f, 0.f, 0.f};
  f32x4 accsX[4];

  #pragma unroll 1
  for (int t0 = 0; t0 < T_; t0 += 16) {
    if (t0) {   // flush previous chunk h (slots 0..15 = steps t0-16..t0-1)
      #pragma unroll
      for (int i = 0; i < 8; ++i) {
        const int uf = tid + i*512;
        const int tl = uf >> 8, sq = (uf >> 4) & 15, us = uf & 15;
        const int ulog = us ^ (sq & 7);
        const bf16x8 v = *reinterpret_cast<const bf16x8*>(
            &ring[tl*2048 + sq*128 + us*8]);
        *reinterpret_cast<bf16x8*>(
            &xh[(size_t)sq*seqStride + (size_t)(t0-16+tl)*HN_ + ulog*8]) = v;
      }
    }
    // stage x chunk t0..t0+15: 4096 16B-units, linear LDS dest,
    // global source pre-swizzled so read-side XOR recovers k-units.
    #pragma unroll
    for (int it = 0; it < 8; ++it) {
      const int U   = tid + it*512;
      const int seq = U >> 8, rem = U & 255;
      const int tl2 = rem >> 4, v = rem & 15;
      const __bf16* src = &xh[(size_t)seq*seqStride + (size_t)(t0+tl2)*HN_
                              + ((v ^ (seq & 7)) << 3)];
      const int Ubase = (tid & ~63) + it*512;
      __builtin_amdgcn_global_load_lds(
          (const __attribute__((address_space(1))) void*)src,
          (__attribute__((address_space(3))) void*)&x_c[Ubase*8], 16, 0, 0);
    }
    __syncthreads();   // drains staging (vmcnt) + flush stores + ring zero

    // accsX = bias + Wih^T @ x(t0)
    {
      bf16x8 bx[4];
      #pragma unroll
      for (int kt = 0; kt < 4; ++kt)
        bx[kt] = *reinterpret_cast<const bf16x8*>(&x_c[lm*2048 + fsw[kt]]);
      #pragma unroll
      for (int nt = 0; nt < 4; ++nt) {
        accsX[nt] = bias_v[nt];
        #pragma unroll
        for (int kt = 0; kt < 4; ++kt)
          accsX[nt] = __builtin_amdgcn_mfma_f32_16x16x32_bf16(wih_f[nt][kt], bx[kt], accsX[nt], 0, 0, 0);
      }
    }

    #pragma unroll
    for (int tl = 0; tl < 16; ++tl) {
      // h_{t-1} from ring slot (tl+15)&15
      const int rbase = ((tl + 15) & 15)*2048 + lm*128;
      bf16x8 bh[4];
      #pragma unroll
      for (int kt = 0; kt < 4; ++kt)
        bh[kt] = *reinterpret_cast<const bf16x8*>(&ring[rbase + fsw[kt]]);

      // z = accsX + Whh^T @ h
      #pragma unroll
      for (int nt = 0; nt < 4; ++nt)
        #pragma unroll
        for (int kt = 0; kt < 4; ++kt)
          accsX[nt] = __builtin_amdgcn_mfma_f32_16x16x32_bf16(whh_f[nt][kt], bh[kt], accsX[nt], 0, 0, 0);

      // x-part for t+1 into fresh accumulators (overlaps the gate phase)
      f32x4 accN[4];
      if (tl < 15) {
        bf16x8 bx[4];
        #pragma unroll
        for (int kt = 0; kt < 4; ++kt)
          bx[kt] = *reinterpret_cast<const bf16x8*>(
              &x_c[lm*2048 + (tl+1)*128 + fsw[kt]]);
        #pragma unroll
        for (int nt = 0; nt < 4; ++nt) {
          accN[nt] = bias_v[nt];
          #pragma unroll
          for (int kt = 0; kt < 4; ++kt)
            accN[nt] = __builtin_amdgcn_mfma_f32_16x16x32_bf16(wih_f[nt][kt], bx[kt], accN[nt], 0, 0, 0);
        }
      }

      // gates fully in-register; write h to ring slot tl (swizzled b16)
      const int wbase = tl*2048 + lm*128;
      #pragma unroll
      for (int nt = 0; nt < 4; ++nt) {
        const float zi = accsX[nt][0], zf = accsX[nt][1];
        const float zg = accsX[nt][2], zo = accsX[nt][3];
        c[nt] = sigf(zf)*c[nt] + sigf(zi)*tanh_fast(zg);
        const float h = sigf(zo)*tanh_fast(c[nt]);
        const int up = (2*w + (nt >> 1)) ^ (lm & 7);
        ring[wbase + up*8 + (nt & 1)*4 + lh] = (__bf16)h;
      }

      if (tl < 15) {
        #pragma unroll
        for (int nt = 0; nt < 4; ++nt) accsX[nt] = accN[nt];
      }
      __syncthreads();
    }
  }
  // final flush (steps 496..511)
  #pragma unroll
  for (int i = 0; i < 8; ++i) {
    const int uf = tid + i*512;
    const int tl = uf >> 8, sq = (uf >> 4) & 15, us = uf & 15;
    const int ulog = us ^ (sq & 7);
    const bf16x8 v = *reinterpret_cast<const bf16x8*>(
        &ring[tl*2048 + sq*128 + us*8]);
    *reinterpret_cast<bf16x8*>(
        &xh[(size_t)sq*seqStride + (size_t)(T_-16+tl)*HN_ + ulog*8]) = v;
  }
}

// ---------------- K4: MFMA gather + classifier (384 -> 256 -> 8), bf16 in
__global__ __launch_bounds__(512, 1) void classifier_mfma_kernel(
    const __bf16* __restrict__ hn, const __bf16* __restrict__ he,
    const float* __restrict__ Wc1, const float* __restrict__ bc1,
    const float* __restrict__ Wc2, const float* __restrict__ bc2,
    float* __restrict__ out)
{
  constexpr int HP = 136;
  constexpr int DP = 264;
  __shared__ __align__(16) __bf16 hn_l[32 * HP];
  __shared__ __align__(16) __bf16 he_l[128 * HP];
  __shared__ __align__(16) __bf16 hid_l[128 * DP];

  const int tid = threadIdx.x;
  const int w   = tid >> 6;
  const int l   = tid & 63;
  const int lm  = l & 15;
  const int lh  = l >> 4;

  bf16x8 wb[2][12];
  float  bcol[2];
  #pragma unroll
  for (int jt = 0; jt < 2; ++jt) {
    const int j = w*32 + jt*16 + lm;
    bcol[jt] = bc1[j];
    #pragma unroll
    for (int kt = 0; kt < 12; ++kt)
      #pragma unroll
      for (int i = 0; i < 8; ++i)
        wb[jt][kt][i] = (__bf16)Wc1[(kt*32 + lh*8 + i)*256 + j];
  }
  bf16x8 wc2f[8];
  const float bc2v = (lm < 8) ? bc2[lm] : 0.f;
  #pragma unroll
  for (int kt = 0; kt < 8; ++kt)
    #pragma unroll
    for (int i = 0; i < 8; ++i)
      wc2f[kt][i] = (lm < 8) ? (__bf16)Wc2[(kt*32 + lh*8 + i)*8 + lm] : (__bf16)0.f;

  for (int g = blockIdx.x; g < 2048; g += 256) {
    const int b  = g >> 6;
    const int t0 = (g & 63) * 8;

    // he: 16 e x 8 t x 128 = 2048 bf16x8 units
    for (int u = tid; u < 2048; u += 512) {
      const int e = u >> 7, rem = u & 127;
      const int tt = rem >> 4, k = (rem & 15)*8;
      const bf16x8 v = *reinterpret_cast<const bf16x8*>(
          &he[((size_t)(b*16+e)*T_ + t0 + tt)*HN_ + k]);
      *reinterpret_cast<bf16x8*>(&he_l[(tt*16 + e)*HP + k]) = v;
    }
    // hn: 4 n x 8 t x 128 = 512 bf16x8 units
    for (int u = tid; u < 512; u += 512) {
      const int n = u >> 7, rem = u & 127;
      const int tt = rem >> 4, k = (rem & 15)*8;
      const bf16x8 v = *reinterpret_cast<const bf16x8*>(
          &hn[((size_t)(b*4+n)*T_ + t0 + tt)*HN_ + k]);
      *reinterpret_cast<bf16x8*>(&hn_l[(tt*4 + n)*HP + k]) = v;
    }
    __syncthreads();

    for (int tt = 0; tt < 8; ++tt) {
      bf16x8 af[12];
      #pragma unroll
      for (int kt = 0; kt < 4; ++kt)
        af[kt] = *reinterpret_cast<const bf16x8*>(
            &hn_l[(tt*4 + (lm>>2))*HP + kt*32 + lh*8]);
      #pragma unroll
      for (int kt = 0; kt < 4; ++kt)
        af[4+kt] = *reinterpret_cast<const bf16x8*>(
            &hn_l[(tt*4 + (lm&3))*HP + kt*32 + lh*8]);
      #pragma unroll
      for (int kt = 0; kt < 4; ++kt)
        af[8+kt] = *reinterpret_cast<const bf16x8*>(
            &he_l[(tt*16 + lm)*HP + kt*32 + lh*8]);
      #pragma unroll
      for (int jt = 0; jt < 2; ++jt) {
        f32x4 acc = { bcol[jt], bcol[jt], bcol[jt], bcol[jt] };
        #pragma unroll
        for (int kt = 0; kt < 12; ++kt)
          acc = __builtin_amdgcn_mfma_f32_16x16x32_bf16(af[kt], wb[jt][kt], acc, 0, 0, 0);
        #pragma unroll
        for (int r = 0; r < 4; ++r)
          hid_l[(tt*16 + lh*4 + r)*DP + (w*2 + jt)*16 + lm] = (__bf16)fmaxf(acc[r], 0.f);
      }
    }
    __syncthreads();

    {
      const int tt = w;
      f32x4 acc = { bc2v, bc2v, bc2v, bc2v };
      #pragma unroll
      for (int kt = 0; kt < 8; ++kt) {
        const bf16x8 a = *reinterpret_cast<const bf16x8*>(
            &hid_l[(tt*16 + lm)*DP + kt*32 + lh*8]);
        acc = __builtin_amdgcn_mfma_f32_16x16x32_bf16(a, wc2f[kt], acc, 0, 0, 0);
      }
      if (lm < 8) {
        const size_t bt = (size_t)b*T_ + t0 + tt;
        #pragma unroll
        for (int r = 0; r < 4; ++r)
          out[(bt*16 + lh*4 + r)*8 + lm] = acc[r];
      }
    }
    __syncthreads();
  }
}

extern "C" void kernel_launch(void* const* d_in, const int* in_sizes, int n_in,
                              void* d_out, int out_size, void* d_ws, size_t ws_size,
                              hipStream_t stream) {
  (void)in_sizes; (void)n_in; (void)out_size; (void)ws_size;
  const float* x_seq = (const float*)d_in[0];
  const float* ea    = (const float*)d_in[1];
  const float* Wn1 = (const float*)d_in[2];
  const float* bn1 = (const float*)d_in[3];
  const float* Wn2 = (const float*)d_in[4];
  const float* bn2 = (const float*)d_in[5];
  const float* We1 = (const float*)d_in[6];
  const float* be1 = (const float*)d_in[7];
  const float* We2 = (const float*)d_in[8];
  const float* be2 = (const float*)d_in[9];
  const float* Wg1 = (const float*)d_in[10];
  const float* bg1 = (const float*)d_in[11];
  const float* Wg2 = (const float*)d_in[12];
  const float* bg2 = (const float*)d_in[13];
  const float* Wef1 = (const float*)d_in[14];
  const float* bef1 = (const float*)d_in[15];
  const float* Wef2 = (const float*)d_in[16];
  const float* bef2 = (const float*)d_in[17];
  const float* Wih_n = (const float*)d_in[18];
  const float* Whh_n = (const float*)d_in[19];
  const float* b_n   = (const float*)d_in[20];
  const float* Wih_e = (const float*)d_in[21];
  const float* Whh_e = (const float*)d_in[22];
  const float* b_e   = (const float*)d_in[23];
  const float* Wc1 = (const float*)d_in[24];
  const float* bc1 = (const float*)d_in[25];
  const float* Wc2 = (const float*)d_in[26];
  const float* bc2 = (const float*)d_in[27];

  // workspace (bf16): xn/hn [128][512][128] (16.8MB), en/he [512][512][128] (67MB)
  __bf16* xn = (__bf16*)d_ws;
  __bf16* en = xn + (size_t)128 * T_ * HN_;
  float* out = (float*)d_out;

  node_mlp_mfma_kernel<<<512, 512, 0, stream>>>(x_seq, Wn1, bn1, Wn2, bn2,
                                                Wg1, bg1, Wg2, bg2, xn);
  edge_mlp_mfma_kernel<<<512, 512, 0, stream>>>(ea, We1, be1, We2, be2,
                                                Wef1, bef1, Wef2, bef2, en);
  // 8 node blocks (128 seqs) + 32 edge blocks (512 seqs), 16 seqs each
  lstm_mfma_kernel<<<40, 512, 0, stream>>>(Wih_n, Whh_n, b_n,
                                           Wih_e, Whh_e, b_e, xn, en);
  classifier_mfma_kernel<<<256, 512, 0, stream>>>(xn, en, Wc1, bc1, Wc2, bc2, out);
}